// Round 1
// baseline (1275.913 us; speedup 1.0000x reference)
//
#include <hip/hip_runtime.h>
#include <math.h>

// B=262144 rows, C=1001 cols, fp32. loss = mean_b log(1 - p_b * w_b),
// p_b = softmax(row_b)[C-1], w_b = (p_b==1.0f) ? 1-1e-6 : 1.
//
// One wave (64 lanes) per row. Lane holds 16 elements (lane + 64k, k<16) in
// registers: single global pass. Butterfly shfl reductions for max and
// sum-exp. Per-row term -> double atomicAdd into 1024 ws slots (spreads
// same-address contention: ~256 atomics/slot). Finalize kernel reduces the
// 1024 slots and divides by B.

#define NROWS 262144
#define NCOLS 1001
#define NSLOT 1024

__global__ __launch_bounds__(256) void adv_loss_kernel(const float* __restrict__ in,
                                                       double* __restrict__ acc) {
    const int wave = threadIdx.x >> 6;
    const int lane = threadIdx.x & 63;
    const int row  = (blockIdx.x << 2) + wave;
    const float* rp = in + (size_t)row * NCOLS;

    float x[16];
#pragma unroll
    for (int k = 0; k < 16; ++k) {
        int idx = lane + (k << 6);
        x[k] = (idx < NCOLS) ? rp[idx] : -INFINITY;
    }

    // row max
    float m = x[0];
#pragma unroll
    for (int k = 1; k < 16; ++k) m = fmaxf(m, x[k]);
#pragma unroll
    for (int off = 1; off < 64; off <<= 1) m = fmaxf(m, __shfl_xor(m, off, 64));

    // sum of exp(x - m); capture e for idx == NCOLS-1 (lane 40, k 15)
    float s = 0.0f, elast = 0.0f;
#pragma unroll
    for (int k = 0; k < 16; ++k) {
        int idx = lane + (k << 6);
        if (idx < NCOLS) {
            float e = __expf(x[k] - m);
            s += e;
            if (idx == NCOLS - 1) elast = e;
        }
    }
#pragma unroll
    for (int off = 1; off < 64; off <<= 1) s += __shfl_xor(s, off, 64);
    elast = __shfl(elast, 40, 64);  // (NCOLS-1) = 40 + 64*15

    if (lane == 0) {
        float p = elast / s;
        float w = (p == 1.0f) ? (1.0f - 1e-6f) : 1.0f;
        float term = logf(1.0f - p * w);
        atomicAdd(&acc[row & (NSLOT - 1)], (double)term);
    }
}

__global__ __launch_bounds__(256) void finalize_kernel(const double* __restrict__ acc,
                                                       float* __restrict__ out) {
    int t = threadIdx.x;
    double s = acc[t] + acc[t + 256] + acc[t + 512] + acc[t + 768];
#pragma unroll
    for (int off = 32; off > 0; off >>= 1) s += __shfl_down(s, off, 64);
    __shared__ double sd[4];
    int wv = t >> 6, lane = t & 63;
    if (lane == 0) sd[wv] = s;
    __syncthreads();
    if (t == 0) {
        double tot = sd[0] + sd[1] + sd[2] + sd[3];
        out[0] = (float)(tot / (double)NROWS);
    }
}

extern "C" void kernel_launch(void* const* d_in, const int* in_sizes, int n_in,
                              void* d_out, int out_size, void* d_ws, size_t ws_size,
                              hipStream_t stream) {
    const float* in = (const float*)d_in[0];  // d_in[1] (target) unused by reference
    double* acc = (double*)d_ws;
    float* out = (float*)d_out;

    hipMemsetAsync(d_ws, 0, NSLOT * sizeof(double), stream);
    adv_loss_kernel<<<NROWS / 4, 256, 0, stream>>>(in, acc);
    finalize_kernel<<<1, 256, 0, stream>>>(acc, out);
}